// Round 9
// baseline (7495.665 us; speedup 1.0000x reference)
//
#include <hip/hip_runtime.h>

#define DI __device__ __forceinline__
DI float silu_f(float x){ return x * (1.0f/(1.0f+__expf(-x))); }

template<int X> struct LOG2 { static constexpr int v = 1 + LOG2<X/2>::v; };
template<> struct LOG2<1> { static constexpr int v = 0; };

// ---------------------------------------------------------------------------
// Direct conv, NHWC in, HWIO weights, LDS-staged weight slices.
// Thread = NPIX pixels x 4 co. G: ci-split (FROZEN per layer — VQ argmin is
// sensitive to latent rounding). CS: co-split across blocks (numerics-free).
// r9: two-phase chunked inner loop — batch-issue global va loads + 16
// ds_read_b128 per 16-ci chunk, then FMA. Per-output fmaf order (ci asc,
// then r) UNCHANGED -> bit-identical output.
// ---------------------------------------------------------------------------
template<int KH,int KW,int STRIDE,int PAD,int CIN,int COUT,int NPIX,
         bool ACT,bool BIAS,int G,int CS>
__global__ __launch_bounds__(256) void conv_k(
    const float* __restrict__ in, const float* __restrict__ w,
    const float* __restrict__ bias, float* __restrict__ out,
    int N,int H,int W,int OH,int OW)
{
  constexpr int CLEN = CIN/G;
  constexpr int COB  = COUT/CS;
  constexpr int COQ  = COB/4;
  constexpr int GSH  = LOG2<G>::v;
  constexpr int CSH  = LOG2<CS>::v;
  constexpr int TAPF = CLEN*COB;
  constexpr bool SALL = (KH*KW*TAPF*4) <= 47*1024;
  constexpr int NTAP = SALL ? KH*KW : KW;
  static_assert(CLEN==3 || (CLEN%4)==0, "ci");
  __shared__ float sw[NTAP*TAPF];

  const int g  = blockIdx.x & (G-1);
  const int cs = (blockIdx.x >> GSH) & (CS-1);
  const int bx = blockIdx.x >> (GSH+CSH);
  const int total = N*OH*OW;
  if (G>1) out += (size_t)g * total * COUT;
  const int ci_off  = g*CLEN;
  const int co_base = cs*COB;

  int idx = bx*256 + (int)threadIdx.x;
  int cq = idx % COQ;
  int pg = idx / COQ;
  int co = cq*4;                 // within block's co slice
  int gco = co_base + co;        // global co
  int p0 = pg*NPIX;

  float acc[NPIX][4] = {};
  int iy0[NPIX], ix0[NPIX]; const float* base[NPIX]; bool pv[NPIX];
#pragma unroll
  for (int t=0;t<NPIX;t++){
    int p=p0+t; pv[t]=(p<total); int pp=pv[t]?p:0;
    int ox=pp%OW; int r=pp/OW; int oy=r%OH; int n=r/OH;
    iy0[t]=oy*STRIDE-PAD; ix0[t]=ox*STRIDE-PAD;
    base[t]=in+(size_t)n*H*W*CIN + ci_off;
  }

  auto stage = [&](int tap0){
    constexpr int TQ = TAPF/4;
    constexpr int V  = NTAP*TQ;
    for (int v=threadIdx.x; v<V; v+=256){
      int tap = v / TQ; int rem = v - tap*TQ;
      float4 q;
      if constexpr (CS==1){
        const float4* src = (const float4*)(w + ((size_t)(tap0+tap)*CIN + ci_off)*COUT);
        q = src[rem];
      } else {
        int ci = rem / (COB/4); int r2 = rem - ci*(COB/4);
        q = *(const float4*)(w + ((size_t)(tap0+tap)*CIN + ci_off + ci)*COUT
                               + co_base + r2*4);
      }
      *(float4*)(sw + (size_t)tap*TAPF + rem*4) = q;
    }
  };

  if constexpr (SALL){
    stage(0);
    __syncthreads();
  }

  for (int ky=0; ky<KH; ky++){
    if constexpr (!SALL){
      __syncthreads();
      stage(ky*KW);
      __syncthreads();
    }
    const float* swr = SALL ? sw + (size_t)ky*KW*TAPF : sw;
    for (int kx=0; kx<KW; kx++){
      const float* swt = swr + (size_t)kx*TAPF;
      const float* ip[NPIX]; bool ok[NPIX];
#pragma unroll
      for (int t=0;t<NPIX;t++){
        int iy=iy0[t]+ky, ix=ix0[t]+kx;
        ok[t]=pv[t] && iy>=0 && iy<H && ix>=0 && ix<W;
        ip[t]=base[t]+(size_t)(iy*W+ix)*CIN;
      }
      if constexpr (CLEN==3){
        float wv[3][4];
        *(float4*)wv[0]=*(const float4*)(swt + 0*COB + co);
        *(float4*)wv[1]=*(const float4*)(swt + 1*COB + co);
        *(float4*)wv[2]=*(const float4*)(swt + 2*COB + co);
#pragma unroll
        for (int t=0;t<NPIX;t++){
          float v0=ok[t]?ip[t][0]:0.f;
          float v1=ok[t]?ip[t][1]:0.f;
          float v2=ok[t]?ip[t][2]:0.f;
#pragma unroll
          for (int j=0;j<4;j++)
            acc[t][j]=fmaf(v0,wv[0][j],fmaf(v1,wv[1][j],fmaf(v2,wv[2][j],acc[t][j])));
        }
      } else {
        constexpr int CHUNK = (NPIX>1) ? 8 : ((CLEN>=16) ? 16 : CLEN);
        static_assert(CLEN % CHUNK == 0, "chunk");
        constexpr int NQ = CHUNK/4;
        for (int ci0=0; ci0<CLEN; ci0+=CHUNK){
          // phase 1a: global input loads (longest latency) — all independent
          float va[NPIX][NQ][4];
#pragma unroll
          for (int t=0;t<NPIX;t++)
#pragma unroll
            for (int q=0;q<NQ;q++)
              *(float4*)va[t][q] = ok[t] ? *(const float4*)(ip[t]+ci0+q*4)
                                         : make_float4(0.f,0.f,0.f,0.f);
          // phase 1b: batched ds_read_b128 — all independent
          float wv[NQ][4][4];
#pragma unroll
          for (int q=0;q<NQ;q++)
#pragma unroll
            for (int r=0;r<4;r++)
              *(float4*)wv[q][r] = *(const float4*)(swt + (ci0+q*4+r)*COB + co);
          // phase 2: FMAs — per-output order (ci asc, r asc) == previous rounds
#pragma unroll
          for (int q=0;q<NQ;q++)
#pragma unroll
            for (int t=0;t<NPIX;t++)
#pragma unroll
              for (int r=0;r<4;r++)
#pragma unroll
                for (int j=0;j<4;j++)
                  acc[t][j]=fmaf(va[t][q][r],wv[q][r][j],acc[t][j]);
        }
      }
    }
  }

  float bv[4]={0.f,0.f,0.f,0.f};
  if constexpr (BIAS) *(float4*)bv = *(const float4*)(bias+gco);
#pragma unroll
  for (int t=0;t<NPIX;t++) if (pv[t]){
    float o[4];
#pragma unroll
    for (int j=0;j<4;j++){
      float v = acc[t][j]+bv[j];
      o[j] = ACT ? silu_f(v) : v;
    }
    *(float4*)(out + (size_t)(p0+t)*COUT + gco) = *(float4*)o;
  }
}

// ---------------------------------------------------------------------------
// reduce G partials (stride n) + bias + optional silu.
// ---------------------------------------------------------------------------
template<int G,int COUT,bool ACT>
__global__ __launch_bounds__(256) void reduce_k(
    const float* __restrict__ p, const float* __restrict__ bias,
    float* __restrict__ out, int n)
{
  int i = (blockIdx.x*256+threadIdx.x)*4;
  if (i>=n) return;
  float a[4]; *(float4*)a = *(const float4*)(p+i);
#pragma unroll
  for (int g=1; g<G; g++){
    float b[4]; *(float4*)b = *(const float4*)(p+(size_t)g*n+i);
#pragma unroll
    for (int j=0;j<4;j++) a[j]+=b[j];
  }
  float bv[4]; *(float4*)bv = *(const float4*)(bias + (i % COUT));
#pragma unroll
  for (int j=0;j<4;j++){
    float v=a[j]+bv[j];
    a[j] = ACT ? silu_f(v) : v;
  }
  *(float4*)(out+i) = *(float4*)a;
}

// ---------------------------------------------------------------------------
// conv_transpose 5x5 s2 SAME (verified r0 mapping), per-tap LDS weight stage.
// parity = b&3, ci-group = (b>>2)&(G-1), spatial = b>>(2+GSH).
// r9: same two-phase chunked inner loop (order-preserving).
// ---------------------------------------------------------------------------
template<int CIN,int COUT,int NPIX,int G,bool DIRECT>
__global__ __launch_bounds__(256) void tconv_k(
    const float* __restrict__ in, const float* __restrict__ w,
    const float* __restrict__ bias, float* __restrict__ out,
    int N,int H,int W,int OH,int OW)
{
  constexpr int COQ  = COUT/4;
  constexpr int CLEN = CIN/G;
  constexpr int GSH  = LOG2<G>::v;
  constexpr int TAPF = CLEN*COUT;
  __shared__ float sw[TAPF];
  const int par = blockIdx.x & 3;
  const int py = par>>1, px = par&1;
  const int g  = (blockIdx.x>>2) & (G-1);
  const int bx = blockIdx.x >> (2+GSH);
  const int NKY = py?3:2, NKX = px?3:2;
  const int OHh=OH>>1, OWh=OW>>1;
  const int total = N*OHh*OWh;
  if (G>1) out += (size_t)g * N*OH*OW*COUT;

  int idx = bx*256 + (int)threadIdx.x;
  int cq = idx % COQ;
  int pg = idx / COQ;
  int co = cq*4;
  int p0 = pg*NPIX;

  float acc[NPIX][4] = {};
  int yy[NPIX], xx[NPIX], nn[NPIX]; const float* base[NPIX]; bool pv[NPIX];
#pragma unroll
  for (int t=0;t<NPIX;t++){
    int p=p0+t; pv[t]=(p<total); int pp=pv[t]?p:0;
    xx[t]=pp%OWh; int r=pp/OWh; yy[t]=r%OHh; nn[t]=r/OHh;
    base[t]=in+(size_t)nn[t]*H*W*CIN + g*CLEN;
  }

  for (int j=0;j<NKY;j++){
    int ky = 2*j + (py?0:1);
    for (int i=0;i<NKX;i++){
      int kx = 2*i + (px?0:1);
      __syncthreads();
      {
        constexpr int V = TAPF/4;
        const float4* src = (const float4*)(w + ((size_t)(ky*5+kx)*CIN + g*CLEN)*COUT);
        for (int v=threadIdx.x; v<V; v+=256) ((float4*)sw)[v]=src[v];
      }
      __syncthreads();
      const float* ip[NPIX]; bool ok[NPIX];
#pragma unroll
      for (int t=0;t<NPIX;t++){
        int iy=yy[t]+j-1, ix=xx[t]+i-1;
        ok[t]=pv[t] && iy>=0 && iy<H && ix>=0 && ix<W;
        ip[t]=base[t]+(size_t)(iy*W+ix)*CIN;
      }
      constexpr int CHUNK = (NPIX>1) ? 8 : ((CLEN>=16) ? 16 : CLEN);
      static_assert(CLEN % CHUNK == 0, "chunk");
      constexpr int NQ = CHUNK/4;
      for (int ci0=0; ci0<CLEN; ci0+=CHUNK){
        float va[NPIX][NQ][4];
#pragma unroll
        for (int t=0;t<NPIX;t++)
#pragma unroll
          for (int q=0;q<NQ;q++)
            *(float4*)va[t][q] = ok[t] ? *(const float4*)(ip[t]+ci0+q*4)
                                       : make_float4(0.f,0.f,0.f,0.f);
        float wv[NQ][4][4];
#pragma unroll
        for (int q=0;q<NQ;q++)
#pragma unroll
          for (int r=0;r<4;r++)
            *(float4*)wv[q][r] = *(const float4*)(sw + (ci0+q*4+r)*COUT + co);
#pragma unroll
        for (int q=0;q<NQ;q++)
#pragma unroll
          for (int t=0;t<NPIX;t++)
#pragma unroll
            for (int r=0;r<4;r++)
#pragma unroll
              for (int jj=0;jj<4;jj++)
                acc[t][jj]=fmaf(va[t][q][r],wv[q][r][jj],acc[t][jj]);
      }
    }
  }

  float bv[4]={0.f,0.f,0.f,0.f};
  if constexpr (DIRECT) *(float4*)bv = *(const float4*)(bias+co);
#pragma unroll
  for (int t=0;t<NPIX;t++) if (pv[t]){
    float o[4];
#pragma unroll
    for (int jj=0;jj<4;jj++){
      float v = acc[t][jj]+bv[jj];
      o[jj] = DIRECT ? silu_f(v) : v;
    }
    *(float4*)(out + (((size_t)nn[t]*OH + (2*yy[t]+py))*OW + (2*xx[t]+px))*COUT + co) = *(float4*)o;
  }
}

// ---------------------------------------------------------------------------
// VQ fused with conv3c 2-partial reduction + bias (round-2 EXACT — FROZEN).
// ---------------------------------------------------------------------------
__global__ __launch_bounds__(256) void vq_k(
    const float* __restrict__ p, const float* __restrict__ bias,
    const float* __restrict__ cb, float* __restrict__ q, int NLat)
{
  __shared__ float slat[4][128];
  int wave = threadIdx.x >> 6;
  int lane = threadIdx.x & 63;
  int l = blockIdx.x*4 + wave;
  if (l >= NLat) return;
  const float* p0 = p + (size_t)l*128;
  const float* p1 = p0 + (size_t)NLat*128;
  slat[wave][lane]    = p0[lane]    + p1[lane]    + bias[lane];
  slat[wave][lane+64] = p0[lane+64] + p1[lane+64] + bias[lane+64];

  float bestd = INFINITY; int besti = 0;
  for (int c0=0;c0<256;c0+=64){
    int c = c0 + lane;
    const float* cp = cb + (size_t)c*128;
    float d = 0.f;
#pragma unroll 8
    for (int k=0;k<128;k+=4){
      float4 cv = *reinterpret_cast<const float4*>(cp+k);
      float d0 = slat[wave][k+0]-cv.x;
      float d1 = slat[wave][k+1]-cv.y;
      float d2 = slat[wave][k+2]-cv.z;
      float d3 = slat[wave][k+3]-cv.w;
      d += d0*d0; d += d1*d1; d += d2*d2; d += d3*d3;
    }
    if (d < bestd) { bestd = d; besti = c; }
  }
  for (int off=32; off; off>>=1){
    float od = __shfl_down(bestd, off);
    int   oi = __shfl_down(besti, off);
    if (od < bestd || (od == bestd && oi < besti)) { bestd=od; besti=oi; }
  }
  besti = __shfl(besti, 0);
  const float* cp = cb + (size_t)besti*128;
  float* qp = q + (size_t)l*128;
  qp[lane]    = cp[lane];
  qp[lane+64] = cp[lane+64];
}

// ---------------------------------------------------------------------------
// Final 3x3 conv 32->3 split over ky rows (g = blockIdx%3). Writes partials.
// ---------------------------------------------------------------------------
__global__ __launch_bounds__(256) void conv_last_k(
    const float* __restrict__ in, const float* __restrict__ w,
    float* __restrict__ p, int N,int H,int W)
{
  int g = blockIdx.x % 3;
  int bx = blockIdx.x / 3;
  int pix = bx*256 + threadIdx.x;
  int total = N*H*W;
  if (pix>=total) return;
  int x = pix % W; int r = pix / W; int y = r % H; int n = r / H;
  float a0=0.f, a1=0.f, a2=0.f;
  int iy = y + g - 1;
  if (iy>=0 && iy<H){
    const float* base = in + ((size_t)n*H + iy)*W*32;
    for (int kx=0;kx<3;kx++){
      int ix=x+kx-1; if(ix<0||ix>=W) continue;
      const float* ip = base + (size_t)ix*32;
      const float* wp = w + (size_t)((g*3+kx)*32)*3;
#pragma unroll
      for (int ci=0;ci<32;ci+=4){
        float va[4]; *(float4*)va = *(const float4*)(ip+ci);
        float wv[12];
        *(float4*)(wv+0) = *(const float4*)(wp+ci*3+0);
        *(float4*)(wv+4) = *(const float4*)(wp+ci*3+4);
        *(float4*)(wv+8) = *(const float4*)(wp+ci*3+8);
#pragma unroll
        for (int r2=0;r2<4;r2++){
          a0 = fmaf(va[r2], wv[r2*3+0], a0);
          a1 = fmaf(va[r2], wv[r2*3+1], a1);
          a2 = fmaf(va[r2], wv[r2*3+2], a2);
        }
      }
    }
  }
  float* pp = p + (size_t)g*total*3 + (size_t)pix*3;
  pp[0]=a0; pp[1]=a1; pp[2]=a2;
}

__global__ __launch_bounds__(256) void reduce_last_k(
    const float* __restrict__ p, const float* __restrict__ bias,
    float* __restrict__ out, int n)
{
  int i = (blockIdx.x*256+threadIdx.x)*4;
  if (i>=n) return;
  float a[4]; *(float4*)a = *(const float4*)(p+i);
#pragma unroll
  for (int g=1; g<3; g++){
    float b[4]; *(float4*)b = *(const float4*)(p+(size_t)g*n+i);
#pragma unroll
    for (int j=0;j<4;j++) a[j]+=b[j];
  }
  float o[4];
#pragma unroll
  for (int j=0;j<4;j++) o[j] = a[j] + bias[(i+j)%3];
  *(float4*)(out+i) = *(float4*)o;
}

extern "C" void kernel_launch(void* const* d_in, const int* in_sizes, int n_in,
                              void* d_out, int out_size, void* d_ws, size_t ws_size,
                              hipStream_t stream) {
  const float* x    = (const float*)d_in[0];
  const float* k1   = (const float*)d_in[1];  const float* b1  = (const float*)d_in[2];
  const float* k1c  = (const float*)d_in[3];  const float* b1c = (const float*)d_in[4];
  const float* k2   = (const float*)d_in[5];  const float* b2  = (const float*)d_in[6];
  const float* k2c  = (const float*)d_in[7];  const float* b2c = (const float*)d_in[8];
  const float* k3   = (const float*)d_in[9];  const float* b3  = (const float*)d_in[10];
  const float* k3c  = (const float*)d_in[11]; const float* b3c = (const float*)d_in[12];
  const float* cb   = (const float*)d_in[13];
  const float* tk1  = (const float*)d_in[14]; const float* tb1  = (const float*)d_in[15];
  const float* tk1c = (const float*)d_in[16]; const float* tb1c = (const float*)d_in[17];
  const float* tk2  = (const float*)d_in[18]; const float* tb2  = (const float*)d_in[19];
  const float* tk2c = (const float*)d_in[20]; const float* tb2c = (const float*)d_in[21];
  const float* tk3  = (const float*)d_in[22]; const float* tb3  = (const float*)d_in[23];
  const float* tk3c = (const float*)d_in[24]; const float* tb3c = (const float*)d_in[25];
  float* out = (float*)d_out;

  float* S  = (float*)d_ws;
  float* W0 = S;                 // [0 .. 1M) floats
  float* W1 = S + 1048576;       // [1M .. 2M)
  float* P  = S + 2097152;       // [2M .. 6M)
  dim3 blk(256);

  // ---- encoder: G-splits + fmaf order FROZEN (VQ argmin) ----
  conv_k<11,11,2,4,  3, 32,1,true ,true ,1,2><<<1024,blk,0,stream>>>(x,  k1,  b1,  W0, 8,128,128,64,64);
  conv_k< 3, 3,1,1, 32, 32,1,true ,true ,1,2><<<1024,blk,0,stream>>>(W0, k1c, b1c, W1, 8,64,64,64,64);
  conv_k<11,11,2,4, 32, 64,1,false,false,2,2><<<1024,blk,0,stream>>>(W1, k2,  nullptr, P, 8,64,64,32,32);
  reduce_k<2, 64,true><<< 512,blk,0,stream>>>(P, b2,  W0, 524288);
  conv_k< 3, 3,1,1, 64, 64,1,true ,true ,1,2><<< 512,blk,0,stream>>>(W0, k2c, b2c, W1, 8,32,32,32,32);
  conv_k<11,11,2,4, 64,128,1,false,false,4,4><<<1024,blk,0,stream>>>(W1, k3,  nullptr, P, 8,32,32,16,16);
  reduce_k<4,128,true><<< 256,blk,0,stream>>>(P, b3,  W0, 262144);
  conv_k< 3, 3,1,1,128,128,1,false,false,2,4><<< 512,blk,0,stream>>>(W0, k3c, nullptr, P, 8,16,16,16,16);
  // ---- VQ: r2-exact 2-partial reduce + argmin + gather (FROZEN) ----
  vq_k<<<512,blk,0,stream>>>(P, b3c, cb, W1, 2048);
  // ---- decoder (G frozen; chunked loads numerics-free) ----
  tconv_k<128,64,1,4,false><<<2048,blk,0,stream>>>(W1, tk1, nullptr, P, 8,16,16,32,32);
  reduce_k<4, 64,true><<< 512,blk,0,stream>>>(P, tb1,  W0, 524288);
  conv_k< 3, 3,1,1, 64, 64,1,false,false,2,2><<<1024,blk,0,stream>>>(W0, tk1c, nullptr, P, 8,32,32,32,32);
  reduce_k<2, 64,true><<< 512,blk,0,stream>>>(P, tb1c, W1, 524288);
  tconv_k< 64,32,1,2,false><<<2048,blk,0,stream>>>(W1, tk2, nullptr, P, 8,32,32,64,64);
  reduce_k<2, 32,true><<<1024,blk,0,stream>>>(P, tb2,  W0, 1048576);
  conv_k< 3, 3,1,1, 32, 32,1,true ,true ,1,2><<<1024,blk,0,stream>>>(W0, tk2c, tb2c, W1, 8,64,64,64,64);
  tconv_k< 32,32,2,1,true ><<<2048,blk,0,stream>>>(W1, tk3, tb3, P, 8,64,64,128,128);
  conv_last_k<<<1536,blk,0,stream>>>(P, tk3c, S, 8,128,128);
  reduce_last_k<<<384,blk,0,stream>>>(S, tb3c, out, 393216);
}

// Round 10
// 673.061 us; speedup vs baseline: 11.1367x; 11.1367x over previous
//
#include <hip/hip_runtime.h>

#define DI __device__ __forceinline__
DI float silu_f(float x){ return x * (1.0f/(1.0f+__expf(-x))); }

template<int X> struct LOG2 { static constexpr int v = 1 + LOG2<X/2>::v; };
template<> struct LOG2<1> { static constexpr int v = 0; };

// ---------------------------------------------------------------------------
// Direct conv, NHWC in, HWIO weights, LDS-staged weight slices.
// Thread = NPIX pixels x 4 co. G: ci-split (FROZEN per layer — VQ argmin is
// sensitive to latent rounding). CS: co-split across blocks (numerics-free).
// r10: CHUNK=8 two-phase batched loads, '#pragma unroll 1' on the chunk loop
// (r9 lesson: without it the compiler fully unrolls + hoists -> 256 VGPR,
// 5GB spill traffic). wv quads are REUSED across NPIX pixels -> NPIX=2
// halves per-FMA LDS traffic (heavy convs are LDS-BW bound: 103us floor at
// NPIX=1 vs 134us measured). Per-output fmaf order (ci asc, r asc) UNCHANGED.
// ---------------------------------------------------------------------------
template<int KH,int KW,int STRIDE,int PAD,int CIN,int COUT,int NPIX,
         bool ACT,bool BIAS,int G,int CS>
__global__ __launch_bounds__(256) void conv_k(
    const float* __restrict__ in, const float* __restrict__ w,
    const float* __restrict__ bias, float* __restrict__ out,
    int N,int H,int W,int OH,int OW)
{
  constexpr int CLEN = CIN/G;
  constexpr int COB  = COUT/CS;
  constexpr int COQ  = COB/4;
  constexpr int GSH  = LOG2<G>::v;
  constexpr int CSH  = LOG2<CS>::v;
  constexpr int TAPF = CLEN*COB;
  constexpr bool SALL = (KH*KW*TAPF*4) <= 47*1024;
  constexpr int NTAP = SALL ? KH*KW : KW;
  static_assert(CLEN==3 || (CLEN%4)==0, "ci");
  __shared__ float sw[NTAP*TAPF];

  const int g  = blockIdx.x & (G-1);
  const int cs = (blockIdx.x >> GSH) & (CS-1);
  const int bx = blockIdx.x >> (GSH+CSH);
  const int total = N*OH*OW;
  if (G>1) out += (size_t)g * total * COUT;
  const int ci_off  = g*CLEN;
  const int co_base = cs*COB;

  int idx = bx*256 + (int)threadIdx.x;
  int cq = idx % COQ;
  int pg = idx / COQ;
  int co = cq*4;                 // within block's co slice
  int gco = co_base + co;        // global co
  int p0 = pg*NPIX;

  float acc[NPIX][4] = {};
  int iy0[NPIX], ix0[NPIX]; const float* base[NPIX]; bool pv[NPIX];
#pragma unroll
  for (int t=0;t<NPIX;t++){
    int p=p0+t; pv[t]=(p<total); int pp=pv[t]?p:0;
    int ox=pp%OW; int r=pp/OW; int oy=r%OH; int n=r/OH;
    iy0[t]=oy*STRIDE-PAD; ix0[t]=ox*STRIDE-PAD;
    base[t]=in+(size_t)n*H*W*CIN + ci_off;
  }

  auto stage = [&](int tap0){
    constexpr int TQ = TAPF/4;
    constexpr int V  = NTAP*TQ;
    for (int v=threadIdx.x; v<V; v+=256){
      int tap = v / TQ; int rem = v - tap*TQ;
      float4 q;
      if constexpr (CS==1){
        const float4* src = (const float4*)(w + ((size_t)(tap0+tap)*CIN + ci_off)*COUT);
        q = src[rem];
      } else {
        int ci = rem / (COB/4); int r2 = rem - ci*(COB/4);
        q = *(const float4*)(w + ((size_t)(tap0+tap)*CIN + ci_off + ci)*COUT
                               + co_base + r2*4);
      }
      *(float4*)(sw + (size_t)tap*TAPF + rem*4) = q;
    }
  };

  if constexpr (SALL){
    stage(0);
    __syncthreads();
  }

  for (int ky=0; ky<KH; ky++){
    if constexpr (!SALL){
      __syncthreads();
      stage(ky*KW);
      __syncthreads();
    }
    const float* swr = SALL ? sw + (size_t)ky*KW*TAPF : sw;
    for (int kx=0; kx<KW; kx++){
      const float* swt = swr + (size_t)kx*TAPF;
      const float* ip[NPIX]; bool ok[NPIX];
#pragma unroll
      for (int t=0;t<NPIX;t++){
        int iy=iy0[t]+ky, ix=ix0[t]+kx;
        ok[t]=pv[t] && iy>=0 && iy<H && ix>=0 && ix<W;
        ip[t]=base[t]+(size_t)(iy*W+ix)*CIN;
      }
      if constexpr (CLEN==3){
        float wv[3][4];
        *(float4*)wv[0]=*(const float4*)(swt + 0*COB + co);
        *(float4*)wv[1]=*(const float4*)(swt + 1*COB + co);
        *(float4*)wv[2]=*(const float4*)(swt + 2*COB + co);
#pragma unroll
        for (int t=0;t<NPIX;t++){
          float v0=ok[t]?ip[t][0]:0.f;
          float v1=ok[t]?ip[t][1]:0.f;
          float v2=ok[t]?ip[t][2]:0.f;
#pragma unroll
          for (int j=0;j<4;j++)
            acc[t][j]=fmaf(v0,wv[0][j],fmaf(v1,wv[1][j],fmaf(v2,wv[2][j],acc[t][j])));
        }
      } else {
        constexpr int CHUNK = (CLEN>=8) ? 8 : CLEN;
        static_assert(CLEN % CHUNK == 0, "chunk");
        constexpr int NQ = CHUNK/4;
#pragma unroll 1
        for (int ci0=0; ci0<CLEN; ci0+=CHUNK){
          // phase 1a: global input loads (longest latency) — independent
          float va[NPIX][NQ][4];
#pragma unroll
          for (int t=0;t<NPIX;t++)
#pragma unroll
            for (int q=0;q<NQ;q++)
              *(float4*)va[t][q] = ok[t] ? *(const float4*)(ip[t]+ci0+q*4)
                                         : make_float4(0.f,0.f,0.f,0.f);
          // phase 1b: batched ds_read_b128 — independent, reused across t
          float wv[NQ][4][4];
#pragma unroll
          for (int q=0;q<NQ;q++)
#pragma unroll
            for (int r=0;r<4;r++)
              *(float4*)wv[q][r] = *(const float4*)(swt + (ci0+q*4+r)*COB + co);
          // phase 2: FMAs — per-output order (ci asc, r asc) == prev rounds
#pragma unroll
          for (int q=0;q<NQ;q++)
#pragma unroll
            for (int t=0;t<NPIX;t++)
#pragma unroll
              for (int r=0;r<4;r++)
#pragma unroll
                for (int j=0;j<4;j++)
                  acc[t][j]=fmaf(va[t][q][r],wv[q][r][j],acc[t][j]);
        }
      }
    }
  }

  float bv[4]={0.f,0.f,0.f,0.f};
  if constexpr (BIAS) *(float4*)bv = *(const float4*)(bias+gco);
#pragma unroll
  for (int t=0;t<NPIX;t++) if (pv[t]){
    float o[4];
#pragma unroll
    for (int j=0;j<4;j++){
      float v = acc[t][j]+bv[j];
      o[j] = ACT ? silu_f(v) : v;
    }
    *(float4*)(out + (size_t)(p0+t)*COUT + gco) = *(float4*)o;
  }
}

// ---------------------------------------------------------------------------
// reduce G partials (stride n) + bias + optional silu.
// ---------------------------------------------------------------------------
template<int G,int COUT,bool ACT>
__global__ __launch_bounds__(256) void reduce_k(
    const float* __restrict__ p, const float* __restrict__ bias,
    float* __restrict__ out, int n)
{
  int i = (blockIdx.x*256+threadIdx.x)*4;
  if (i>=n) return;
  float a[4]; *(float4*)a = *(const float4*)(p+i);
#pragma unroll
  for (int g=1; g<G; g++){
    float b[4]; *(float4*)b = *(const float4*)(p+(size_t)g*n+i);
#pragma unroll
    for (int j=0;j<4;j++) a[j]+=b[j];
  }
  float bv[4]; *(float4*)bv = *(const float4*)(bias + (i % COUT));
#pragma unroll
  for (int j=0;j<4;j++){
    float v=a[j]+bv[j];
    a[j] = ACT ? silu_f(v) : v;
  }
  *(float4*)(out+i) = *(float4*)a;
}

// ---------------------------------------------------------------------------
// conv_transpose 5x5 s2 SAME (verified r0 mapping), per-tap LDS weight stage.
// parity = b&3, ci-group = (b>>2)&(G-1), spatial = b>>(2+GSH).
// r10: same CHUNK=8 / unroll-1 batched inner loop (order-preserving).
// ---------------------------------------------------------------------------
template<int CIN,int COUT,int NPIX,int G,bool DIRECT>
__global__ __launch_bounds__(256) void tconv_k(
    const float* __restrict__ in, const float* __restrict__ w,
    const float* __restrict__ bias, float* __restrict__ out,
    int N,int H,int W,int OH,int OW)
{
  constexpr int COQ  = COUT/4;
  constexpr int CLEN = CIN/G;
  constexpr int GSH  = LOG2<G>::v;
  constexpr int TAPF = CLEN*COUT;
  __shared__ float sw[TAPF];
  const int par = blockIdx.x & 3;
  const int py = par>>1, px = par&1;
  const int g  = (blockIdx.x>>2) & (G-1);
  const int bx = blockIdx.x >> (2+GSH);
  const int NKY = py?3:2, NKX = px?3:2;
  const int OHh=OH>>1, OWh=OW>>1;
  const int total = N*OHh*OWh;
  if (G>1) out += (size_t)g * N*OH*OW*COUT;

  int idx = bx*256 + (int)threadIdx.x;
  int cq = idx % COQ;
  int pg = idx / COQ;
  int co = cq*4;
  int p0 = pg*NPIX;

  float acc[NPIX][4] = {};
  int yy[NPIX], xx[NPIX], nn[NPIX]; const float* base[NPIX]; bool pv[NPIX];
#pragma unroll
  for (int t=0;t<NPIX;t++){
    int p=p0+t; pv[t]=(p<total); int pp=pv[t]?p:0;
    xx[t]=pp%OWh; int r=pp/OWh; yy[t]=r%OHh; nn[t]=r/OHh;
    base[t]=in+(size_t)nn[t]*H*W*CIN + g*CLEN;
  }

  for (int j=0;j<NKY;j++){
    int ky = 2*j + (py?0:1);
    for (int i=0;i<NKX;i++){
      int kx = 2*i + (px?0:1);
      __syncthreads();
      {
        constexpr int V = TAPF/4;
        const float4* src = (const float4*)(w + ((size_t)(ky*5+kx)*CIN + g*CLEN)*COUT);
        for (int v=threadIdx.x; v<V; v+=256) ((float4*)sw)[v]=src[v];
      }
      __syncthreads();
      const float* ip[NPIX]; bool ok[NPIX];
#pragma unroll
      for (int t=0;t<NPIX;t++){
        int iy=yy[t]+j-1, ix=xx[t]+i-1;
        ok[t]=pv[t] && iy>=0 && iy<H && ix>=0 && ix<W;
        ip[t]=base[t]+(size_t)(iy*W+ix)*CIN;
      }
      constexpr int CHUNK = (CLEN>=8) ? 8 : CLEN;
      static_assert(CLEN % CHUNK == 0, "chunk");
      constexpr int NQ = CHUNK/4;
#pragma unroll 1
      for (int ci0=0; ci0<CLEN; ci0+=CHUNK){
        float va[NPIX][NQ][4];
#pragma unroll
        for (int t=0;t<NPIX;t++)
#pragma unroll
          for (int q=0;q<NQ;q++)
            *(float4*)va[t][q] = ok[t] ? *(const float4*)(ip[t]+ci0+q*4)
                                       : make_float4(0.f,0.f,0.f,0.f);
        float wv[NQ][4][4];
#pragma unroll
        for (int q=0;q<NQ;q++)
#pragma unroll
          for (int r=0;r<4;r++)
            *(float4*)wv[q][r] = *(const float4*)(sw + (ci0+q*4+r)*COUT + co);
#pragma unroll
        for (int q=0;q<NQ;q++)
#pragma unroll
          for (int t=0;t<NPIX;t++)
#pragma unroll
            for (int r=0;r<4;r++)
#pragma unroll
              for (int jj=0;jj<4;jj++)
                acc[t][jj]=fmaf(va[t][q][r],wv[q][r][jj],acc[t][jj]);
      }
    }
  }

  float bv[4]={0.f,0.f,0.f,0.f};
  if constexpr (DIRECT) *(float4*)bv = *(const float4*)(bias+co);
#pragma unroll
  for (int t=0;t<NPIX;t++) if (pv[t]){
    float o[4];
#pragma unroll
    for (int jj=0;jj<4;jj++){
      float v = acc[t][jj]+bv[jj];
      o[jj] = DIRECT ? silu_f(v) : v;
    }
    *(float4*)(out + (((size_t)nn[t]*OH + (2*yy[t]+py))*OW + (2*xx[t]+px))*COUT + co) = *(float4*)o;
  }
}

// ---------------------------------------------------------------------------
// VQ fused with conv3c 2-partial reduction + bias (round-2 EXACT — FROZEN).
// ---------------------------------------------------------------------------
__global__ __launch_bounds__(256) void vq_k(
    const float* __restrict__ p, const float* __restrict__ bias,
    const float* __restrict__ cb, float* __restrict__ q, int NLat)
{
  __shared__ float slat[4][128];
  int wave = threadIdx.x >> 6;
  int lane = threadIdx.x & 63;
  int l = blockIdx.x*4 + wave;
  if (l >= NLat) return;
  const float* p0 = p + (size_t)l*128;
  const float* p1 = p0 + (size_t)NLat*128;
  slat[wave][lane]    = p0[lane]    + p1[lane]    + bias[lane];
  slat[wave][lane+64] = p0[lane+64] + p1[lane+64] + bias[lane+64];

  float bestd = INFINITY; int besti = 0;
  for (int c0=0;c0<256;c0+=64){
    int c = c0 + lane;
    const float* cp = cb + (size_t)c*128;
    float d = 0.f;
#pragma unroll 8
    for (int k=0;k<128;k+=4){
      float4 cv = *reinterpret_cast<const float4*>(cp+k);
      float d0 = slat[wave][k+0]-cv.x;
      float d1 = slat[wave][k+1]-cv.y;
      float d2 = slat[wave][k+2]-cv.z;
      float d3 = slat[wave][k+3]-cv.w;
      d += d0*d0; d += d1*d1; d += d2*d2; d += d3*d3;
    }
    if (d < bestd) { bestd = d; besti = c; }
  }
  for (int off=32; off; off>>=1){
    float od = __shfl_down(bestd, off);
    int   oi = __shfl_down(besti, off);
    if (od < bestd || (od == bestd && oi < besti)) { bestd=od; besti=oi; }
  }
  besti = __shfl(besti, 0);
  const float* cp = cb + (size_t)besti*128;
  float* qp = q + (size_t)l*128;
  qp[lane]    = cp[lane];
  qp[lane+64] = cp[lane+64];
}

// ---------------------------------------------------------------------------
// Final 3x3 conv 32->3 split over ky rows (g = blockIdx%3). Writes partials.
// ---------------------------------------------------------------------------
__global__ __launch_bounds__(256) void conv_last_k(
    const float* __restrict__ in, const float* __restrict__ w,
    float* __restrict__ p, int N,int H,int W)
{
  int g = blockIdx.x % 3;
  int bx = blockIdx.x / 3;
  int pix = bx*256 + threadIdx.x;
  int total = N*H*W;
  if (pix>=total) return;
  int x = pix % W; int r = pix / W; int y = r % H; int n = r / H;
  float a0=0.f, a1=0.f, a2=0.f;
  int iy = y + g - 1;
  if (iy>=0 && iy<H){
    const float* base = in + ((size_t)n*H + iy)*W*32;
    for (int kx=0;kx<3;kx++){
      int ix=x+kx-1; if(ix<0||ix>=W) continue;
      const float* ip = base + (size_t)ix*32;
      const float* wp = w + (size_t)((g*3+kx)*32)*3;
#pragma unroll
      for (int ci=0;ci<32;ci+=4){
        float va[4]; *(float4*)va = *(const float4*)(ip+ci);
        float wv[12];
        *(float4*)(wv+0) = *(const float4*)(wp+ci*3+0);
        *(float4*)(wv+4) = *(const float4*)(wp+ci*3+4);
        *(float4*)(wv+8) = *(const float4*)(wp+ci*3+8);
#pragma unroll
        for (int r2=0;r2<4;r2++){
          a0 = fmaf(va[r2], wv[r2*3+0], a0);
          a1 = fmaf(va[r2], wv[r2*3+1], a1);
          a2 = fmaf(va[r2], wv[r2*3+2], a2);
        }
      }
    }
  }
  float* pp = p + (size_t)g*total*3 + (size_t)pix*3;
  pp[0]=a0; pp[1]=a1; pp[2]=a2;
}

__global__ __launch_bounds__(256) void reduce_last_k(
    const float* __restrict__ p, const float* __restrict__ bias,
    float* __restrict__ out, int n)
{
  int i = (blockIdx.x*256+threadIdx.x)*4;
  if (i>=n) return;
  float a[4]; *(float4*)a = *(const float4*)(p+i);
#pragma unroll
  for (int g=1; g<3; g++){
    float b[4]; *(float4*)b = *(const float4*)(p+(size_t)g*n+i);
#pragma unroll
    for (int j=0;j<4;j++) a[j]+=b[j];
  }
  float o[4];
#pragma unroll
  for (int j=0;j<4;j++) o[j] = a[j] + bias[(i+j)%3];
  *(float4*)(out+i) = *(float4*)o;
}

extern "C" void kernel_launch(void* const* d_in, const int* in_sizes, int n_in,
                              void* d_out, int out_size, void* d_ws, size_t ws_size,
                              hipStream_t stream) {
  const float* x    = (const float*)d_in[0];
  const float* k1   = (const float*)d_in[1];  const float* b1  = (const float*)d_in[2];
  const float* k1c  = (const float*)d_in[3];  const float* b1c = (const float*)d_in[4];
  const float* k2   = (const float*)d_in[5];  const float* b2  = (const float*)d_in[6];
  const float* k2c  = (const float*)d_in[7];  const float* b2c = (const float*)d_in[8];
  const float* k3   = (const float*)d_in[9];  const float* b3  = (const float*)d_in[10];
  const float* k3c  = (const float*)d_in[11]; const float* b3c = (const float*)d_in[12];
  const float* cb   = (const float*)d_in[13];
  const float* tk1  = (const float*)d_in[14]; const float* tb1  = (const float*)d_in[15];
  const float* tk1c = (const float*)d_in[16]; const float* tb1c = (const float*)d_in[17];
  const float* tk2  = (const float*)d_in[18]; const float* tb2  = (const float*)d_in[19];
  const float* tk2c = (const float*)d_in[20]; const float* tb2c = (const float*)d_in[21];
  const float* tk3  = (const float*)d_in[22]; const float* tb3  = (const float*)d_in[23];
  const float* tk3c = (const float*)d_in[24]; const float* tb3c = (const float*)d_in[25];
  float* out = (float*)d_out;

  float* S  = (float*)d_ws;
  float* W0 = S;                 // [0 .. 1M) floats
  float* W1 = S + 1048576;       // [1M .. 2M)
  float* P  = S + 2097152;       // [2M .. 6M)
  dim3 blk(256);

  // ---- encoder: G-splits + fmaf order FROZEN (VQ argmin) ----
  conv_k<11,11,2,4,  3, 32,1,true ,true ,1,2><<<1024,blk,0,stream>>>(x,  k1,  b1,  W0, 8,128,128,64,64);
  conv_k< 3, 3,1,1, 32, 32,1,true ,true ,1,2><<<1024,blk,0,stream>>>(W0, k1c, b1c, W1, 8,64,64,64,64);
  // conv2: NPIX=2 (halves LDS-BW floor), G2 CS2, 512 blocks, LDS 22.5KB
  conv_k<11,11,2,4, 32, 64,2,false,false,2,2><<< 512,blk,0,stream>>>(W1, k2,  nullptr, P, 8,64,64,32,32);
  reduce_k<2, 64,true><<< 512,blk,0,stream>>>(P, b2,  W0, 524288);
  conv_k< 3, 3,1,1, 64, 64,1,true ,true ,1,2><<< 512,blk,0,stream>>>(W0, k2c, b2c, W1, 8,32,32,32,32);
  // conv3: NPIX=2, G4 CS4, 512 blocks, LDS 22.5KB
  conv_k<11,11,2,4, 64,128,2,false,false,4,4><<< 512,blk,0,stream>>>(W1, k3,  nullptr, P, 8,32,32,16,16);
  reduce_k<4,128,true><<< 256,blk,0,stream>>>(P, b3,  W0, 262144);
  conv_k< 3, 3,1,1,128,128,1,false,false,2,4><<< 512,blk,0,stream>>>(W0, k3c, nullptr, P, 8,16,16,16,16);
  // ---- VQ: r2-exact 2-partial reduce + argmin + gather (FROZEN) ----
  vq_k<<<512,blk,0,stream>>>(P, b3c, cb, W1, 2048);
  // ---- decoder (G frozen; NPIX/chunking numerics-free) ----
  tconv_k<128,64,2,4,false><<<1024,blk,0,stream>>>(W1, tk1, nullptr, P, 8,16,16,32,32);
  reduce_k<4, 64,true><<< 512,blk,0,stream>>>(P, tb1,  W0, 524288);
  conv_k< 3, 3,1,1, 64, 64,1,false,false,2,2><<<1024,blk,0,stream>>>(W0, tk1c, nullptr, P, 8,32,32,32,32);
  reduce_k<2, 64,true><<< 512,blk,0,stream>>>(P, tb1c, W1, 524288);
  tconv_k< 64,32,2,2,false><<<1024,blk,0,stream>>>(W1, tk2, nullptr, P, 8,32,32,64,64);
  reduce_k<2, 32,true><<<1024,blk,0,stream>>>(P, tb2,  W0, 1048576);
  conv_k< 3, 3,1,1, 32, 32,1,true ,true ,1,2><<<1024,blk,0,stream>>>(W0, tk2c, tb2c, W1, 8,64,64,64,64);
  tconv_k< 32,32,2,1,true ><<<2048,blk,0,stream>>>(W1, tk3, tb3, P, 8,64,64,128,128);
  conv_last_k<<<1536,blk,0,stream>>>(P, tk3c, S, 8,128,128);
  reduce_last_k<<<384,blk,0,stream>>>(S, tb3c, out, 393216);
}

// Round 11
// 660.791 us; speedup vs baseline: 11.3435x; 1.0186x over previous
//
#include <hip/hip_runtime.h>

#define DI __device__ __forceinline__
DI float silu_f(float x){ return x * (1.0f/(1.0f+__expf(-x))); }

template<int X> struct LOG2 { static constexpr int v = 1 + LOG2<X/2>::v; };
template<> struct LOG2<1> { static constexpr int v = 0; };

// ---------------------------------------------------------------------------
// Direct conv, NHWC in, HWIO weights, LDS-staged weight slices.
// Thread = NPIX pixels x CPT co. G: ci-split (FROZEN per layer — VQ argmin is
// sensitive to latent rounding). CS: co-split across blocks (numerics-free).
// CPT: co-per-thread 4 or 2 (numerics-free — each output's full fmaf chain
// ky->kx->ci->r stays on one thread). r11: CPT=2 doubles thread count ->
// 8 waves/SIMD on the heavy convs (r8<->r10 A/B proved latency-bound:
// 4 w/SIMD = 43% VALU/134us, 2 w/SIMD = 32%/178us). CS sized so LDS <= 18KB
// (never caps residency below grid/256 blocks per CU). CHUNK=8 + unroll 1
// batched loads (r9 lesson: full unroll hoists -> 256 VGPR spills).
// ---------------------------------------------------------------------------
template<int KH,int KW,int STRIDE,int PAD,int CIN,int COUT,int NPIX,
         bool ACT,bool BIAS,int G,int CS,int CPT>
__global__ __launch_bounds__(256) void conv_k(
    const float* __restrict__ in, const float* __restrict__ w,
    const float* __restrict__ bias, float* __restrict__ out,
    int N,int H,int W,int OH,int OW)
{
  constexpr int CLEN = CIN/G;
  constexpr int COB  = COUT/CS;
  constexpr int COQ  = COB/CPT;
  constexpr int GSH  = LOG2<G>::v;
  constexpr int CSH  = LOG2<CS>::v;
  constexpr int TAPF = CLEN*COB;
  constexpr bool SALL = (KH*KW*TAPF*4) <= 47*1024;
  constexpr int NTAP = SALL ? KH*KW : KW;
  static_assert(CLEN==3 || (CLEN%4)==0, "ci");
  static_assert(CPT==2 || CPT==4, "cpt");
  __shared__ float sw[NTAP*TAPF];

  const int g  = blockIdx.x & (G-1);
  const int cs = (blockIdx.x >> GSH) & (CS-1);
  const int bx = blockIdx.x >> (GSH+CSH);
  const int total = N*OH*OW;
  if (G>1) out += (size_t)g * total * COUT;
  const int ci_off  = g*CLEN;
  const int co_base = cs*COB;

  int idx = bx*256 + (int)threadIdx.x;
  int cq = idx % COQ;
  int pg = idx / COQ;
  int co = cq*CPT;               // within block's co slice
  int gco = co_base + co;        // global co
  int p0 = pg*NPIX;

  float acc[NPIX][CPT] = {};
  int iy0[NPIX], ix0[NPIX]; const float* base[NPIX]; bool pv[NPIX];
#pragma unroll
  for (int t=0;t<NPIX;t++){
    int p=p0+t; pv[t]=(p<total); int pp=pv[t]?p:0;
    int ox=pp%OW; int r=pp/OW; int oy=r%OH; int n=r/OH;
    iy0[t]=oy*STRIDE-PAD; ix0[t]=ox*STRIDE-PAD;
    base[t]=in+(size_t)n*H*W*CIN + ci_off;
  }

  auto stage = [&](int tap0){
    constexpr int TQ = TAPF/4;
    constexpr int V  = NTAP*TQ;
    for (int v=threadIdx.x; v<V; v+=256){
      int tap = v / TQ; int rem = v - tap*TQ;
      float4 q;
      if constexpr (CS==1){
        const float4* src = (const float4*)(w + ((size_t)(tap0+tap)*CIN + ci_off)*COUT);
        q = src[rem];
      } else {
        int ci = rem / (COB/4); int r2 = rem - ci*(COB/4);
        q = *(const float4*)(w + ((size_t)(tap0+tap)*CIN + ci_off + ci)*COUT
                               + co_base + r2*4);
      }
      *(float4*)(sw + (size_t)tap*TAPF + rem*4) = q;
    }
  };

  if constexpr (SALL){
    stage(0);
    __syncthreads();
  }

  for (int ky=0; ky<KH; ky++){
    if constexpr (!SALL){
      __syncthreads();
      stage(ky*KW);
      __syncthreads();
    }
    const float* swr = SALL ? sw + (size_t)ky*KW*TAPF : sw;
    for (int kx=0; kx<KW; kx++){
      const float* swt = swr + (size_t)kx*TAPF;
      const float* ip[NPIX]; bool ok[NPIX];
#pragma unroll
      for (int t=0;t<NPIX;t++){
        int iy=iy0[t]+ky, ix=ix0[t]+kx;
        ok[t]=pv[t] && iy>=0 && iy<H && ix>=0 && ix<W;
        ip[t]=base[t]+(size_t)(iy*W+ix)*CIN;
      }
      if constexpr (CLEN==3){
        float wv[3][CPT];
#pragma unroll
        for (int k=0;k<3;k++){
          if constexpr (CPT==4) *(float4*)wv[k] = *(const float4*)(swt + k*COB + co);
          else                  *(float2*)wv[k] = *(const float2*)(swt + k*COB + co);
        }
#pragma unroll
        for (int t=0;t<NPIX;t++){
          float v0=ok[t]?ip[t][0]:0.f;
          float v1=ok[t]?ip[t][1]:0.f;
          float v2=ok[t]?ip[t][2]:0.f;
#pragma unroll
          for (int j=0;j<CPT;j++)
            acc[t][j]=fmaf(v0,wv[0][j],fmaf(v1,wv[1][j],fmaf(v2,wv[2][j],acc[t][j])));
        }
      } else {
        constexpr int CHUNK = (CLEN>=8) ? 8 : CLEN;
        static_assert(CLEN % CHUNK == 0, "chunk");
        constexpr int NQ = CHUNK/4;
#pragma unroll 1
        for (int ci0=0; ci0<CLEN; ci0+=CHUNK){
          // phase 1a: global input loads (longest latency) — independent
          float va[NPIX][NQ][4];
#pragma unroll
          for (int t=0;t<NPIX;t++)
#pragma unroll
            for (int q=0;q<NQ;q++)
              *(float4*)va[t][q] = ok[t] ? *(const float4*)(ip[t]+ci0+q*4)
                                         : make_float4(0.f,0.f,0.f,0.f);
          // phase 1b: batched LDS weight reads — independent, broadcast
          float wv[NQ][4][CPT];
#pragma unroll
          for (int q=0;q<NQ;q++)
#pragma unroll
            for (int r=0;r<4;r++){
              if constexpr (CPT==4)
                *(float4*)wv[q][r] = *(const float4*)(swt + (ci0+q*4+r)*COB + co);
              else
                *(float2*)wv[q][r] = *(const float2*)(swt + (ci0+q*4+r)*COB + co);
            }
          // phase 2: FMAs — per-output order (ci asc, r asc) == prev rounds
#pragma unroll
          for (int q=0;q<NQ;q++)
#pragma unroll
            for (int t=0;t<NPIX;t++)
#pragma unroll
              for (int r=0;r<4;r++)
#pragma unroll
                for (int j=0;j<CPT;j++)
                  acc[t][j]=fmaf(va[t][q][r],wv[q][r][j],acc[t][j]);
        }
      }
    }
  }

  float bv[CPT] = {};
  if constexpr (BIAS){
    if constexpr (CPT==4) *(float4*)bv = *(const float4*)(bias+gco);
    else                  *(float2*)bv = *(const float2*)(bias+gco);
  }
#pragma unroll
  for (int t=0;t<NPIX;t++) if (pv[t]){
    float o[CPT];
#pragma unroll
    for (int j=0;j<CPT;j++){
      float v = acc[t][j]+bv[j];
      o[j] = ACT ? silu_f(v) : v;
    }
    if constexpr (CPT==4) *(float4*)(out + (size_t)(p0+t)*COUT + gco) = *(float4*)o;
    else                  *(float2*)(out + (size_t)(p0+t)*COUT + gco) = *(float2*)o;
  }
}

// ---------------------------------------------------------------------------
// reduce G partials (stride n) + bias + optional silu.
// ---------------------------------------------------------------------------
template<int G,int COUT,bool ACT>
__global__ __launch_bounds__(256) void reduce_k(
    const float* __restrict__ p, const float* __restrict__ bias,
    float* __restrict__ out, int n)
{
  int i = (blockIdx.x*256+threadIdx.x)*4;
  if (i>=n) return;
  float a[4]; *(float4*)a = *(const float4*)(p+i);
#pragma unroll
  for (int g=1; g<G; g++){
    float b[4]; *(float4*)b = *(const float4*)(p+(size_t)g*n+i);
#pragma unroll
    for (int j=0;j<4;j++) a[j]+=b[j];
  }
  float bv[4]; *(float4*)bv = *(const float4*)(bias + (i % COUT));
#pragma unroll
  for (int j=0;j<4;j++){
    float v=a[j]+bv[j];
    a[j] = ACT ? silu_f(v) : v;
  }
  *(float4*)(out+i) = *(float4*)a;
}

// ---------------------------------------------------------------------------
// conv_transpose 5x5 s2 SAME (verified r0 mapping), per-tap LDS weight stage.
// parity = b&3, ci-group = (b>>2)&(G-1), spatial = b>>(2+GSH).
// (r8-proven configs: all 2048-block launches, 8 waves/SIMD already.)
// ---------------------------------------------------------------------------
template<int CIN,int COUT,int NPIX,int G,bool DIRECT>
__global__ __launch_bounds__(256) void tconv_k(
    const float* __restrict__ in, const float* __restrict__ w,
    const float* __restrict__ bias, float* __restrict__ out,
    int N,int H,int W,int OH,int OW)
{
  constexpr int COQ  = COUT/4;
  constexpr int CLEN = CIN/G;
  constexpr int GSH  = LOG2<G>::v;
  constexpr int TAPF = CLEN*COUT;
  __shared__ float sw[TAPF];
  const int par = blockIdx.x & 3;
  const int py = par>>1, px = par&1;
  const int g  = (blockIdx.x>>2) & (G-1);
  const int bx = blockIdx.x >> (2+GSH);
  const int NKY = py?3:2, NKX = px?3:2;
  const int OHh=OH>>1, OWh=OW>>1;
  const int total = N*OHh*OWh;
  if (G>1) out += (size_t)g * N*OH*OW*COUT;

  int idx = bx*256 + (int)threadIdx.x;
  int cq = idx % COQ;
  int pg = idx / COQ;
  int co = cq*4;
  int p0 = pg*NPIX;

  float acc[NPIX][4] = {};
  int yy[NPIX], xx[NPIX], nn[NPIX]; const float* base[NPIX]; bool pv[NPIX];
#pragma unroll
  for (int t=0;t<NPIX;t++){
    int p=p0+t; pv[t]=(p<total); int pp=pv[t]?p:0;
    xx[t]=pp%OWh; int r=pp/OWh; yy[t]=r%OHh; nn[t]=r/OHh;
    base[t]=in+(size_t)nn[t]*H*W*CIN + g*CLEN;
  }

  for (int j=0;j<NKY;j++){
    int ky = 2*j + (py?0:1);
    for (int i=0;i<NKX;i++){
      int kx = 2*i + (px?0:1);
      __syncthreads();
      {
        constexpr int V = TAPF/4;
        const float4* src = (const float4*)(w + ((size_t)(ky*5+kx)*CIN + g*CLEN)*COUT);
        for (int v=threadIdx.x; v<V; v+=256) ((float4*)sw)[v]=src[v];
      }
      __syncthreads();
      const float* ip[NPIX]; bool ok[NPIX];
#pragma unroll
      for (int t=0;t<NPIX;t++){
        int iy=yy[t]+j-1, ix=xx[t]+i-1;
        ok[t]=pv[t] && iy>=0 && iy<H && ix>=0 && ix<W;
        ip[t]=base[t]+(size_t)(iy*W+ix)*CIN;
      }
      constexpr int CHUNK = (CLEN>=8) ? 8 : CLEN;
      static_assert(CLEN % CHUNK == 0, "chunk");
      constexpr int NQ = CHUNK/4;
#pragma unroll 1
      for (int ci0=0; ci0<CLEN; ci0+=CHUNK){
        float va[NPIX][NQ][4];
#pragma unroll
        for (int t=0;t<NPIX;t++)
#pragma unroll
          for (int q=0;q<NQ;q++)
            *(float4*)va[t][q] = ok[t] ? *(const float4*)(ip[t]+ci0+q*4)
                                       : make_float4(0.f,0.f,0.f,0.f);
        float wv[NQ][4][4];
#pragma unroll
        for (int q=0;q<NQ;q++)
#pragma unroll
          for (int r=0;r<4;r++)
            *(float4*)wv[q][r] = *(const float4*)(sw + (ci0+q*4+r)*COUT + co);
#pragma unroll
        for (int q=0;q<NQ;q++)
#pragma unroll
          for (int t=0;t<NPIX;t++)
#pragma unroll
            for (int r=0;r<4;r++)
#pragma unroll
              for (int jj=0;jj<4;jj++)
                acc[t][jj]=fmaf(va[t][q][r],wv[q][r][jj],acc[t][jj]);
      }
    }
  }

  float bv[4]={0.f,0.f,0.f,0.f};
  if constexpr (DIRECT) *(float4*)bv = *(const float4*)(bias+co);
#pragma unroll
  for (int t=0;t<NPIX;t++) if (pv[t]){
    float o[4];
#pragma unroll
    for (int jj=0;jj<4;jj++){
      float v = acc[t][jj]+bv[jj];
      o[jj] = DIRECT ? silu_f(v) : v;
    }
    *(float4*)(out + (((size_t)nn[t]*OH + (2*yy[t]+py))*OW + (2*xx[t]+px))*COUT + co) = *(float4*)o;
  }
}

// ---------------------------------------------------------------------------
// VQ fused with conv3c 2-partial reduction + bias (round-2 EXACT — FROZEN).
// ---------------------------------------------------------------------------
__global__ __launch_bounds__(256) void vq_k(
    const float* __restrict__ p, const float* __restrict__ bias,
    const float* __restrict__ cb, float* __restrict__ q, int NLat)
{
  __shared__ float slat[4][128];
  int wave = threadIdx.x >> 6;
  int lane = threadIdx.x & 63;
  int l = blockIdx.x*4 + wave;
  if (l >= NLat) return;
  const float* p0 = p + (size_t)l*128;
  const float* p1 = p0 + (size_t)NLat*128;
  slat[wave][lane]    = p0[lane]    + p1[lane]    + bias[lane];
  slat[wave][lane+64] = p0[lane+64] + p1[lane+64] + bias[lane+64];

  float bestd = INFINITY; int besti = 0;
  for (int c0=0;c0<256;c0+=64){
    int c = c0 + lane;
    const float* cp = cb + (size_t)c*128;
    float d = 0.f;
#pragma unroll 8
    for (int k=0;k<128;k+=4){
      float4 cv = *reinterpret_cast<const float4*>(cp+k);
      float d0 = slat[wave][k+0]-cv.x;
      float d1 = slat[wave][k+1]-cv.y;
      float d2 = slat[wave][k+2]-cv.z;
      float d3 = slat[wave][k+3]-cv.w;
      d += d0*d0; d += d1*d1; d += d2*d2; d += d3*d3;
    }
    if (d < bestd) { bestd = d; besti = c; }
  }
  for (int off=32; off; off>>=1){
    float od = __shfl_down(bestd, off);
    int   oi = __shfl_down(besti, off);
    if (od < bestd || (od == bestd && oi < besti)) { bestd=od; besti=oi; }
  }
  besti = __shfl(besti, 0);
  const float* cp = cb + (size_t)besti*128;
  float* qp = q + (size_t)l*128;
  qp[lane]    = cp[lane];
  qp[lane+64] = cp[lane+64];
}

// ---------------------------------------------------------------------------
// Final 3x3 conv 32->3 split over ky rows (g = blockIdx%3). Writes partials.
// ---------------------------------------------------------------------------
__global__ __launch_bounds__(256) void conv_last_k(
    const float* __restrict__ in, const float* __restrict__ w,
    float* __restrict__ p, int N,int H,int W)
{
  int g = blockIdx.x % 3;
  int bx = blockIdx.x / 3;
  int pix = bx*256 + threadIdx.x;
  int total = N*H*W;
  if (pix>=total) return;
  int x = pix % W; int r = pix / W; int y = r % H; int n = r / H;
  float a0=0.f, a1=0.f, a2=0.f;
  int iy = y + g - 1;
  if (iy>=0 && iy<H){
    const float* base = in + ((size_t)n*H + iy)*W*32;
    for (int kx=0;kx<3;kx++){
      int ix=x+kx-1; if(ix<0||ix>=W) continue;
      const float* ip = base + (size_t)ix*32;
      const float* wp = w + (size_t)((g*3+kx)*32)*3;
#pragma unroll
      for (int ci=0;ci<32;ci+=4){
        float va[4]; *(float4*)va = *(const float4*)(ip+ci);
        float wv[12];
        *(float4*)(wv+0) = *(const float4*)(wp+ci*3+0);
        *(float4*)(wv+4) = *(const float4*)(wp+ci*3+4);
        *(float4*)(wv+8) = *(const float4*)(wp+ci*3+8);
#pragma unroll
        for (int r2=0;r2<4;r2++){
          a0 = fmaf(va[r2], wv[r2*3+0], a0);
          a1 = fmaf(va[r2], wv[r2*3+1], a1);
          a2 = fmaf(va[r2], wv[r2*3+2], a2);
        }
      }
    }
  }
  float* pp = p + (size_t)g*total*3 + (size_t)pix*3;
  pp[0]=a0; pp[1]=a1; pp[2]=a2;
}

__global__ __launch_bounds__(256) void reduce_last_k(
    const float* __restrict__ p, const float* __restrict__ bias,
    float* __restrict__ out, int n)
{
  int i = (blockIdx.x*256+threadIdx.x)*4;
  if (i>=n) return;
  float a[4]; *(float4*)a = *(const float4*)(p+i);
#pragma unroll
  for (int g=1; g<3; g++){
    float b[4]; *(float4*)b = *(const float4*)(p+(size_t)g*n+i);
#pragma unroll
    for (int j=0;j<4;j++) a[j]+=b[j];
  }
  float o[4];
#pragma unroll
  for (int j=0;j<4;j++) o[j] = a[j] + bias[(i+j)%3];
  *(float4*)(out+i) = *(float4*)o;
}

extern "C" void kernel_launch(void* const* d_in, const int* in_sizes, int n_in,
                              void* d_out, int out_size, void* d_ws, size_t ws_size,
                              hipStream_t stream) {
  const float* x    = (const float*)d_in[0];
  const float* k1   = (const float*)d_in[1];  const float* b1  = (const float*)d_in[2];
  const float* k1c  = (const float*)d_in[3];  const float* b1c = (const float*)d_in[4];
  const float* k2   = (const float*)d_in[5];  const float* b2  = (const float*)d_in[6];
  const float* k2c  = (const float*)d_in[7];  const float* b2c = (const float*)d_in[8];
  const float* k3   = (const float*)d_in[9];  const float* b3  = (const float*)d_in[10];
  const float* k3c  = (const float*)d_in[11]; const float* b3c = (const float*)d_in[12];
  const float* cb   = (const float*)d_in[13];
  const float* tk1  = (const float*)d_in[14]; const float* tb1  = (const float*)d_in[15];
  const float* tk1c = (const float*)d_in[16]; const float* tb1c = (const float*)d_in[17];
  const float* tk2  = (const float*)d_in[18]; const float* tb2  = (const float*)d_in[19];
  const float* tk2c = (const float*)d_in[20]; const float* tb2c = (const float*)d_in[21];
  const float* tk3  = (const float*)d_in[22]; const float* tb3  = (const float*)d_in[23];
  const float* tk3c = (const float*)d_in[24]; const float* tb3c = (const float*)d_in[25];
  float* out = (float*)d_out;

  float* S  = (float*)d_ws;
  float* W0 = S;                 // [0 .. 1M) floats
  float* W1 = S + 1048576;       // [1M .. 2M)
  float* P  = S + 2097152;       // [2M .. 6M)
  dim3 blk(256);

  // ---- encoder: G-splits + fmaf order FROZEN (VQ argmin). CPT=2, CS sized
  //      so LDS <= 18KB; heavy convs at 2048 blocks = 8 waves/SIMD ----
  // conv1: CS4 CPT2 -> 2048 blocks, stage-all 11.6KB
  conv_k<11,11,2,4,  3, 32,1,true ,true ,1,4,2><<<2048,blk,0,stream>>>(x,  k1,  b1,  W0, 8,128,128,64,64);
  // conv1c: CS2 CPT2 -> 2048 blocks, stage-all 18KB
  conv_k< 3, 3,1,1, 32, 32,1,true ,true ,1,2,2><<<2048,blk,0,stream>>>(W0, k1c, b1c, W1, 8,64,64,64,64);
  // conv2: G2 CS4 CPT2 -> 2048 blocks, per-ky 11.3KB
  conv_k<11,11,2,4, 32, 64,1,false,false,2,4,2><<<2048,blk,0,stream>>>(W1, k2,  nullptr, P, 8,64,64,32,32);
  reduce_k<2, 64,true><<< 512,blk,0,stream>>>(P, b2,  W0, 524288);
  // conv2c: CS8 CPT2 -> 1024 blocks, stage-all 18KB
  conv_k< 3, 3,1,1, 64, 64,1,true ,true ,1,8,2><<<1024,blk,0,stream>>>(W0, k2c, b2c, W1, 8,32,32,32,32);
  // conv3: G4 CS8 CPT2 -> 2048 blocks, per-ky 11.3KB
  conv_k<11,11,2,4, 64,128,1,false,false,4,8,2><<<2048,blk,0,stream>>>(W1, k3,  nullptr, P, 8,32,32,16,16);
  reduce_k<4,128,true><<< 256,blk,0,stream>>>(P, b3,  W0, 262144);
  // conv3c: G2 CS8 CPT2 -> 1024 blocks, stage-all 36KB (4/CU needed, fits)
  conv_k< 3, 3,1,1,128,128,1,false,false,2,8,2><<<1024,blk,0,stream>>>(W0, k3c, nullptr, P, 8,16,16,16,16);
  // ---- VQ: r2-exact 2-partial reduce + argmin + gather (FROZEN) ----
  vq_k<<<512,blk,0,stream>>>(P, b3c, cb, W1, 2048);
  // ---- decoder (r8-proven tconv configs; small convs CPT2) ----
  tconv_k<128,64,1,4,false><<<2048,blk,0,stream>>>(W1, tk1, nullptr, P, 8,16,16,32,32);
  reduce_k<4, 64,true><<< 512,blk,0,stream>>>(P, tb1,  W0, 524288);
  // tk1c: G2 CS4 CPT2 -> 2048 blocks, stage-all 18KB
  conv_k< 3, 3,1,1, 64, 64,1,false,false,2,4,2><<<2048,blk,0,stream>>>(W0, tk1c, nullptr, P, 8,32,32,32,32);
  reduce_k<2, 64,true><<< 512,blk,0,stream>>>(P, tb1c, W1, 524288);
  tconv_k< 64,32,1,2,false><<<2048,blk,0,stream>>>(W1, tk2, nullptr, P, 8,32,32,64,64);
  reduce_k<2, 32,true><<<1024,blk,0,stream>>>(P, tb2,  W0, 1048576);
  // tk2c: CS2 CPT2 -> 2048 blocks, stage-all 18KB
  conv_k< 3, 3,1,1, 32, 32,1,true ,true ,1,2,2><<<2048,blk,0,stream>>>(W0, tk2c, tb2c, W1, 8,64,64,64,64);
  tconv_k< 32,32,2,1,true ><<<2048,blk,0,stream>>>(W1, tk3, tb3, P, 8,64,64,128,128);
  conv_last_k<<<1536,blk,0,stream>>>(P, tk3c, S, 8,128,128);
  reduce_last_k<<<384,blk,0,stream>>>(S, tb3c, out, 393216);
}

// Round 12
// 583.807 us; speedup vs baseline: 12.8393x; 1.1319x over previous
//
#include <hip/hip_runtime.h>

#define DI __device__ __forceinline__
DI float silu_f(float x){ return x * (1.0f/(1.0f+__expf(-x))); }

template<int X> struct LOG2 { static constexpr int v = 1 + LOG2<X/2>::v; };
template<> struct LOG2<1> { static constexpr int v = 0; };

typedef float f32x2 __attribute__((ext_vector_type(2)));
DI f32x2 pk_fma(f32x2 a, f32x2 b, f32x2 c){
#if __has_builtin(__builtin_elementwise_fma)
  return __builtin_elementwise_fma(a,b,c);
#else
  f32x2 r; r[0]=fmaf(a[0],b[0],c[0]); r[1]=fmaf(a[1],b[1],c[1]); return r;
#endif
}

// ---------------------------------------------------------------------------
// Direct conv, NHWC in, HWIO weights, LDS-staged weight slices (r8 config).
// Thread = NPIX pixels x 4 co. G: ci-split (FROZEN — VQ argmin is sensitive
// to latent rounding). CS: co-split across blocks (numerics-free).
// r12: (a) CHUNK=8 two-phase batched loads + unroll 1 (r10-proven codegen,
// VGPR 44) at r8's NPIX1 grids; (b) acc packed as f32x2 -> v_pk_fma_f32
// (2 IEEE FMAs/instr, bit-identical per chain; chain order ky->kx->ci->r
// unchanged). r8<->r10<->r11 A/B: 4 waves/SIMD @ eff 3.2 is the optimum
// mapping; this round cuts instructions at that fixed mapping.
// ---------------------------------------------------------------------------
template<int KH,int KW,int STRIDE,int PAD,int CIN,int COUT,int NPIX,
         bool ACT,bool BIAS,int G,int CS>
__global__ __launch_bounds__(256) void conv_k(
    const float* __restrict__ in, const float* __restrict__ w,
    const float* __restrict__ bias, float* __restrict__ out,
    int N,int H,int W,int OH,int OW)
{
  constexpr int CLEN = CIN/G;
  constexpr int COB  = COUT/CS;
  constexpr int COQ  = COB/4;
  constexpr int GSH  = LOG2<G>::v;
  constexpr int CSH  = LOG2<CS>::v;
  constexpr int TAPF = CLEN*COB;
  constexpr bool SALL = (KH*KW*TAPF*4) <= 47*1024;
  constexpr int NTAP = SALL ? KH*KW : KW;
  static_assert(CLEN==3 || (CLEN%4)==0, "ci");
  __shared__ float sw[NTAP*TAPF];

  const int g  = blockIdx.x & (G-1);
  const int cs = (blockIdx.x >> GSH) & (CS-1);
  const int bx = blockIdx.x >> (GSH+CSH);
  const int total = N*OH*OW;
  if (G>1) out += (size_t)g * total * COUT;
  const int ci_off  = g*CLEN;
  const int co_base = cs*COB;

  int idx = bx*256 + (int)threadIdx.x;
  int cq = idx % COQ;
  int pg = idx / COQ;
  int co = cq*4;                 // within block's co slice
  int gco = co_base + co;        // global co
  int p0 = pg*NPIX;

  f32x2 acc2[NPIX][2] = {};
  int iy0[NPIX], ix0[NPIX]; const float* base[NPIX]; bool pv[NPIX];
#pragma unroll
  for (int t=0;t<NPIX;t++){
    int p=p0+t; pv[t]=(p<total); int pp=pv[t]?p:0;
    int ox=pp%OW; int r=pp/OW; int oy=r%OH; int n=r/OH;
    iy0[t]=oy*STRIDE-PAD; ix0[t]=ox*STRIDE-PAD;
    base[t]=in+(size_t)n*H*W*CIN + ci_off;
  }

  auto stage = [&](int tap0){
    constexpr int TQ = TAPF/4;
    constexpr int V  = NTAP*TQ;
    for (int v=threadIdx.x; v<V; v+=256){
      int tap = v / TQ; int rem = v - tap*TQ;
      float4 q;
      if constexpr (CS==1){
        const float4* src = (const float4*)(w + ((size_t)(tap0+tap)*CIN + ci_off)*COUT);
        q = src[rem];
      } else {
        int ci = rem / (COB/4); int r2 = rem - ci*(COB/4);
        q = *(const float4*)(w + ((size_t)(tap0+tap)*CIN + ci_off + ci)*COUT
                               + co_base + r2*4);
      }
      *(float4*)(sw + (size_t)tap*TAPF + rem*4) = q;
    }
  };

  if constexpr (SALL){
    stage(0);
    __syncthreads();
  }

  for (int ky=0; ky<KH; ky++){
    if constexpr (!SALL){
      __syncthreads();
      stage(ky*KW);
      __syncthreads();
    }
    const float* swr = SALL ? sw + (size_t)ky*KW*TAPF : sw;
    for (int kx=0; kx<KW; kx++){
      const float* swt = swr + (size_t)kx*TAPF;
      const float* ip[NPIX]; bool ok[NPIX];
#pragma unroll
      for (int t=0;t<NPIX;t++){
        int iy=iy0[t]+ky, ix=ix0[t]+kx;
        ok[t]=pv[t] && iy>=0 && iy<H && ix>=0 && ix<W;
        ip[t]=base[t]+(size_t)(iy*W+ix)*CIN;
      }
      if constexpr (CLEN==3){
        float wv[3][4];
        *(float4*)wv[0]=*(const float4*)(swt + 0*COB + co);
        *(float4*)wv[1]=*(const float4*)(swt + 1*COB + co);
        *(float4*)wv[2]=*(const float4*)(swt + 2*COB + co);
#pragma unroll
        for (int t=0;t<NPIX;t++){
          float v0=ok[t]?ip[t][0]:0.f;
          float v1=ok[t]?ip[t][1]:0.f;
          float v2=ok[t]?ip[t][2]:0.f;
#pragma unroll
          for (int h=0;h<2;h++){
            // per-component nesting identical to fmaf(v0,w0,fmaf(v1,w1,fmaf(v2,w2,acc)))
            f32x2 a = pk_fma((f32x2){v2,v2}, (f32x2){wv[2][2*h],wv[2][2*h+1]}, acc2[t][h]);
            a       = pk_fma((f32x2){v1,v1}, (f32x2){wv[1][2*h],wv[1][2*h+1]}, a);
            acc2[t][h] = pk_fma((f32x2){v0,v0}, (f32x2){wv[0][2*h],wv[0][2*h+1]}, a);
          }
        }
      } else {
        constexpr int CHUNK = (CLEN>=8) ? 8 : CLEN;
        static_assert(CLEN % CHUNK == 0, "chunk");
        constexpr int NQ = CHUNK/4;
#pragma unroll 1
        for (int ci0=0; ci0<CLEN; ci0+=CHUNK){
          // phase 1a: global input loads — independent
          float va[NPIX][NQ][4];
#pragma unroll
          for (int t=0;t<NPIX;t++)
#pragma unroll
            for (int q=0;q<NQ;q++)
              *(float4*)va[t][q] = ok[t] ? *(const float4*)(ip[t]+ci0+q*4)
                                         : make_float4(0.f,0.f,0.f,0.f);
          // phase 1b: batched ds_read_b128 weights — independent
          float wv[NQ][4][4];
#pragma unroll
          for (int q=0;q<NQ;q++)
#pragma unroll
            for (int r=0;r<4;r++)
              *(float4*)wv[q][r] = *(const float4*)(swt + (ci0+q*4+r)*COB + co);
          // phase 2: packed FMAs — per-output chain order (ci asc, r asc)
          // identical to r8; v_pk_fma_f32 = 2 independent IEEE FMAs.
#pragma unroll
          for (int q=0;q<NQ;q++)
#pragma unroll
            for (int t=0;t<NPIX;t++)
#pragma unroll
              for (int r=0;r<4;r++){
                f32x2 vb = {va[t][q][r], va[t][q][r]};
                acc2[t][0] = pk_fma(vb, (f32x2){wv[q][r][0],wv[q][r][1]}, acc2[t][0]);
                acc2[t][1] = pk_fma(vb, (f32x2){wv[q][r][2],wv[q][r][3]}, acc2[t][1]);
              }
        }
      }
    }
  }

  float bv[4]={0.f,0.f,0.f,0.f};
  if constexpr (BIAS) *(float4*)bv = *(const float4*)(bias+gco);
#pragma unroll
  for (int t=0;t<NPIX;t++) if (pv[t]){
    float o[4];
#pragma unroll
    for (int j=0;j<4;j++){
      float v = acc2[t][j>>1][j&1]+bv[j];
      o[j] = ACT ? silu_f(v) : v;
    }
    *(float4*)(out + (size_t)(p0+t)*COUT + gco) = *(float4*)o;
  }
}

// ---------------------------------------------------------------------------
// reduce G partials (stride n) + bias + optional silu. (FROZEN)
// ---------------------------------------------------------------------------
template<int G,int COUT,bool ACT>
__global__ __launch_bounds__(256) void reduce_k(
    const float* __restrict__ p, const float* __restrict__ bias,
    float* __restrict__ out, int n)
{
  int i = (blockIdx.x*256+threadIdx.x)*4;
  if (i>=n) return;
  float a[4]; *(float4*)a = *(const float4*)(p+i);
#pragma unroll
  for (int g=1; g<G; g++){
    float b[4]; *(float4*)b = *(const float4*)(p+(size_t)g*n+i);
#pragma unroll
    for (int j=0;j<4;j++) a[j]+=b[j];
  }
  float bv[4]; *(float4*)bv = *(const float4*)(bias + (i % COUT));
#pragma unroll
  for (int j=0;j<4;j++){
    float v=a[j]+bv[j];
    a[j] = ACT ? silu_f(v) : v;
  }
  *(float4*)(out+i) = *(float4*)a;
}

// ---------------------------------------------------------------------------
// conv_transpose 5x5 s2 SAME (verified r0 mapping), per-tap LDS weight stage.
// parity = b&3, ci-group = (b>>2)&(G-1), spatial = b>>(2+GSH). r8 grids.
// r12: CHUNK8/unroll1 + pk_fma (order-preserving, decoder anyway).
// ---------------------------------------------------------------------------
template<int CIN,int COUT,int NPIX,int G,bool DIRECT>
__global__ __launch_bounds__(256) void tconv_k(
    const float* __restrict__ in, const float* __restrict__ w,
    const float* __restrict__ bias, float* __restrict__ out,
    int N,int H,int W,int OH,int OW)
{
  constexpr int COQ  = COUT/4;
  constexpr int CLEN = CIN/G;
  constexpr int GSH  = LOG2<G>::v;
  constexpr int TAPF = CLEN*COUT;
  __shared__ float sw[TAPF];
  const int par = blockIdx.x & 3;
  const int py = par>>1, px = par&1;
  const int g  = (blockIdx.x>>2) & (G-1);
  const int bx = blockIdx.x >> (2+GSH);
  const int NKY = py?3:2, NKX = px?3:2;
  const int OHh=OH>>1, OWh=OW>>1;
  const int total = N*OHh*OWh;
  if (G>1) out += (size_t)g * N*OH*OW*COUT;

  int idx = bx*256 + (int)threadIdx.x;
  int cq = idx % COQ;
  int pg = idx / COQ;
  int co = cq*4;
  int p0 = pg*NPIX;

  f32x2 acc2[NPIX][2] = {};
  int yy[NPIX], xx[NPIX], nn[NPIX]; const float* base[NPIX]; bool pv[NPIX];
#pragma unroll
  for (int t=0;t<NPIX;t++){
    int p=p0+t; pv[t]=(p<total); int pp=pv[t]?p:0;
    xx[t]=pp%OWh; int r=pp/OWh; yy[t]=r%OHh; nn[t]=r/OHh;
    base[t]=in+(size_t)nn[t]*H*W*CIN + g*CLEN;
  }

  for (int j=0;j<NKY;j++){
    int ky = 2*j + (py?0:1);
    for (int i=0;i<NKX;i++){
      int kx = 2*i + (px?0:1);
      __syncthreads();
      {
        constexpr int V = TAPF/4;
        const float4* src = (const float4*)(w + ((size_t)(ky*5+kx)*CIN + g*CLEN)*COUT);
        for (int v=threadIdx.x; v<V; v+=256) ((float4*)sw)[v]=src[v];
      }
      __syncthreads();
      const float* ip[NPIX]; bool ok[NPIX];
#pragma unroll
      for (int t=0;t<NPIX;t++){
        int iy=yy[t]+j-1, ix=xx[t]+i-1;
        ok[t]=pv[t] && iy>=0 && iy<H && ix>=0 && ix<W;
        ip[t]=base[t]+(size_t)(iy*W+ix)*CIN;
      }
      constexpr int CHUNK = (CLEN>=8) ? 8 : CLEN;
      static_assert(CLEN % CHUNK == 0, "chunk");
      constexpr int NQ = CHUNK/4;
#pragma unroll 1
      for (int ci0=0; ci0<CLEN; ci0+=CHUNK){
        float va[NPIX][NQ][4];
#pragma unroll
        for (int t=0;t<NPIX;t++)
#pragma unroll
          for (int q=0;q<NQ;q++)
            *(float4*)va[t][q] = ok[t] ? *(const float4*)(ip[t]+ci0+q*4)
                                       : make_float4(0.f,0.f,0.f,0.f);
        float wv[NQ][4][4];
#pragma unroll
        for (int q=0;q<NQ;q++)
#pragma unroll
          for (int r=0;r<4;r++)
            *(float4*)wv[q][r] = *(const float4*)(sw + (ci0+q*4+r)*COUT + co);
#pragma unroll
        for (int q=0;q<NQ;q++)
#pragma unroll
          for (int t=0;t<NPIX;t++)
#pragma unroll
            for (int r=0;r<4;r++){
              f32x2 vb = {va[t][q][r], va[t][q][r]};
              acc2[t][0] = pk_fma(vb, (f32x2){wv[q][r][0],wv[q][r][1]}, acc2[t][0]);
              acc2[t][1] = pk_fma(vb, (f32x2){wv[q][r][2],wv[q][r][3]}, acc2[t][1]);
            }
      }
    }
  }

  float bv[4]={0.f,0.f,0.f,0.f};
  if constexpr (DIRECT) *(float4*)bv = *(const float4*)(bias+co);
#pragma unroll
  for (int t=0;t<NPIX;t++) if (pv[t]){
    float o[4];
#pragma unroll
    for (int jj=0;jj<4;jj++){
      float v = acc2[t][jj>>1][jj&1]+bv[jj];
      o[jj] = DIRECT ? silu_f(v) : v;
    }
    *(float4*)(out + (((size_t)nn[t]*OH + (2*yy[t]+py))*OW + (2*xx[t]+px))*COUT + co) = *(float4*)o;
  }
}

// ---------------------------------------------------------------------------
// VQ fused with conv3c 2-partial reduction + bias (round-2 EXACT — FROZEN).
// ---------------------------------------------------------------------------
__global__ __launch_bounds__(256) void vq_k(
    const float* __restrict__ p, const float* __restrict__ bias,
    const float* __restrict__ cb, float* __restrict__ q, int NLat)
{
  __shared__ float slat[4][128];
  int wave = threadIdx.x >> 6;
  int lane = threadIdx.x & 63;
  int l = blockIdx.x*4 + wave;
  if (l >= NLat) return;
  const float* p0 = p + (size_t)l*128;
  const float* p1 = p0 + (size_t)NLat*128;
  slat[wave][lane]    = p0[lane]    + p1[lane]    + bias[lane];
  slat[wave][lane+64] = p0[lane+64] + p1[lane+64] + bias[lane+64];

  float bestd = INFINITY; int besti = 0;
  for (int c0=0;c0<256;c0+=64){
    int c = c0 + lane;
    const float* cp = cb + (size_t)c*128;
    float d = 0.f;
#pragma unroll 8
    for (int k=0;k<128;k+=4){
      float4 cv = *reinterpret_cast<const float4*>(cp+k);
      float d0 = slat[wave][k+0]-cv.x;
      float d1 = slat[wave][k+1]-cv.y;
      float d2 = slat[wave][k+2]-cv.z;
      float d3 = slat[wave][k+3]-cv.w;
      d += d0*d0; d += d1*d1; d += d2*d2; d += d3*d3;
    }
    if (d < bestd) { bestd = d; besti = c; }
  }
  for (int off=32; off; off>>=1){
    float od = __shfl_down(bestd, off);
    int   oi = __shfl_down(besti, off);
    if (od < bestd || (od == bestd && oi < besti)) { bestd=od; besti=oi; }
  }
  besti = __shfl(besti, 0);
  const float* cp = cb + (size_t)besti*128;
  float* qp = q + (size_t)l*128;
  qp[lane]    = cp[lane];
  qp[lane+64] = cp[lane+64];
}

// ---------------------------------------------------------------------------
// Final 3x3 conv 32->3 split over ky rows (g = blockIdx%3). Writes partials.
// ---------------------------------------------------------------------------
__global__ __launch_bounds__(256) void conv_last_k(
    const float* __restrict__ in, const float* __restrict__ w,
    float* __restrict__ p, int N,int H,int W)
{
  int g = blockIdx.x % 3;
  int bx = blockIdx.x / 3;
  int pix = bx*256 + threadIdx.x;
  int total = N*H*W;
  if (pix>=total) return;
  int x = pix % W; int r = pix / W; int y = r % H; int n = r / H;
  float a0=0.f, a1=0.f, a2=0.f;
  int iy = y + g - 1;
  if (iy>=0 && iy<H){
    const float* base = in + ((size_t)n*H + iy)*W*32;
    for (int kx=0;kx<3;kx++){
      int ix=x+kx-1; if(ix<0||ix>=W) continue;
      const float* ip = base + (size_t)ix*32;
      const float* wp = w + (size_t)((g*3+kx)*32)*3;
#pragma unroll
      for (int ci=0;ci<32;ci+=4){
        float va[4]; *(float4*)va = *(const float4*)(ip+ci);
        float wv[12];
        *(float4*)(wv+0) = *(const float4*)(wp+ci*3+0);
        *(float4*)(wv+4) = *(const float4*)(wp+ci*3+4);
        *(float4*)(wv+8) = *(const float4*)(wp+ci*3+8);
#pragma unroll
        for (int r2=0;r2<4;r2++){
          a0 = fmaf(va[r2], wv[r2*3+0], a0);
          a1 = fmaf(va[r2], wv[r2*3+1], a1);
          a2 = fmaf(va[r2], wv[r2*3+2], a2);
        }
      }
    }
  }
  float* pp = p + (size_t)g*total*3 + (size_t)pix*3;
  pp[0]=a0; pp[1]=a1; pp[2]=a2;
}

__global__ __launch_bounds__(256) void reduce_last_k(
    const float* __restrict__ p, const float* __restrict__ bias,
    float* __restrict__ out, int n)
{
  int i = (blockIdx.x*256+threadIdx.x)*4;
  if (i>=n) return;
  float a[4]; *(float4*)a = *(const float4*)(p+i);
#pragma unroll
  for (int g=1; g<3; g++){
    float b[4]; *(float4*)b = *(const float4*)(p+(size_t)g*n+i);
#pragma unroll
    for (int j=0;j<4;j++) a[j]+=b[j];
  }
  float o[4];
#pragma unroll
  for (int j=0;j<4;j++) o[j] = a[j] + bias[(i+j)%3];
  *(float4*)(out+i) = *(float4*)o;
}

extern "C" void kernel_launch(void* const* d_in, const int* in_sizes, int n_in,
                              void* d_out, int out_size, void* d_ws, size_t ws_size,
                              hipStream_t stream) {
  const float* x    = (const float*)d_in[0];
  const float* k1   = (const float*)d_in[1];  const float* b1  = (const float*)d_in[2];
  const float* k1c  = (const float*)d_in[3];  const float* b1c = (const float*)d_in[4];
  const float* k2   = (const float*)d_in[5];  const float* b2  = (const float*)d_in[6];
  const float* k2c  = (const float*)d_in[7];  const float* b2c = (const float*)d_in[8];
  const float* k3   = (const float*)d_in[9];  const float* b3  = (const float*)d_in[10];
  const float* k3c  = (const float*)d_in[11]; const float* b3c = (const float*)d_in[12];
  const float* cb   = (const float*)d_in[13];
  const float* tk1  = (const float*)d_in[14]; const float* tb1  = (const float*)d_in[15];
  const float* tk1c = (const float*)d_in[16]; const float* tb1c = (const float*)d_in[17];
  const float* tk2  = (const float*)d_in[18]; const float* tb2  = (const float*)d_in[19];
  const float* tk2c = (const float*)d_in[20]; const float* tb2c = (const float*)d_in[21];
  const float* tk3  = (const float*)d_in[22]; const float* tb3  = (const float*)d_in[23];
  const float* tk3c = (const float*)d_in[24]; const float* tb3c = (const float*)d_in[25];
  float* out = (float*)d_out;

  float* S  = (float*)d_ws;
  float* W0 = S;                 // [0 .. 1M) floats
  float* W1 = S + 1048576;       // [1M .. 2M)
  float* P  = S + 2097152;       // [2M .. 6M)
  dim3 blk(256);

  // ---- r8-EXACT grids/configs (proven 572us); only inner loop changed ----
  conv_k<11,11,2,4,  3, 32,1,true ,true ,1,2><<<1024,blk,0,stream>>>(x,  k1,  b1,  W0, 8,128,128,64,64);
  conv_k< 3, 3,1,1, 32, 32,1,true ,true ,1,2><<<1024,blk,0,stream>>>(W0, k1c, b1c, W1, 8,64,64,64,64);
  conv_k<11,11,2,4, 32, 64,1,false,false,2,2><<<1024,blk,0,stream>>>(W1, k2,  nullptr, P, 8,64,64,32,32);
  reduce_k<2, 64,true><<< 512,blk,0,stream>>>(P, b2,  W0, 524288);
  conv_k< 3, 3,1,1, 64, 64,1,true ,true ,1,2><<< 512,blk,0,stream>>>(W0, k2c, b2c, W1, 8,32,32,32,32);
  conv_k<11,11,2,4, 64,128,1,false,false,4,4><<<1024,blk,0,stream>>>(W1, k3,  nullptr, P, 8,32,32,16,16);
  reduce_k<4,128,true><<< 256,blk,0,stream>>>(P, b3,  W0, 262144);
  conv_k< 3, 3,1,1,128,128,1,false,false,2,4><<< 512,blk,0,stream>>>(W0, k3c, nullptr, P, 8,16,16,16,16);
  // ---- VQ: r2-exact 2-partial reduce + argmin + gather (FROZEN) ----
  vq_k<<<512,blk,0,stream>>>(P, b3c, cb, W1, 2048);
  // ---- decoder (r8 grids) ----
  tconv_k<128,64,1,4,false><<<2048,blk,0,stream>>>(W1, tk1, nullptr, P, 8,16,16,32,32);
  reduce_k<4, 64,true><<< 512,blk,0,stream>>>(P, tb1,  W0, 524288);
  conv_k< 3, 3,1,1, 64, 64,1,false,false,2,2><<<1024,blk,0,stream>>>(W0, tk1c, nullptr, P, 8,32,32,32,32);
  reduce_k<2, 64,true><<< 512,blk,0,stream>>>(P, tb1c, W1, 524288);
  tconv_k< 64,32,1,2,false><<<2048,blk,0,stream>>>(W1, tk2, nullptr, P, 8,32,32,64,64);
  reduce_k<2, 32,true><<<1024,blk,0,stream>>>(P, tb2,  W0, 1048576);
  conv_k< 3, 3,1,1, 32, 32,1,true ,true ,1,2><<<1024,blk,0,stream>>>(W0, tk2c, tb2c, W1, 8,64,64,64,64);
  tconv_k< 32,32,2,1,true ><<<2048,blk,0,stream>>>(W1, tk3, tb3, P, 8,64,64,128,128);
  conv_last_k<<<1536,blk,0,stream>>>(P, tk3c, S, 8,128,128);
  reduce_last_k<<<384,blk,0,stream>>>(S, tb3c, out, 393216);
}